// Round 3
// baseline (76.255 us; speedup 1.0000x reference)
//
#include <hip/hip_runtime.h>

// PositionalEncoding: out[b,s,d] = x[b,s,d] + (positions[b,s] >= 0 ? pe[positions[b,s], d] : 0)
// B=256, S=365, D=512, fp32. Memory-bound streaming add with gathered PE rows.
//
// Round 2 -> 3 changes (theory: L2 pollution + MLP):
//  - nontemporal load of x / nontemporal store of out: the 383 MB stream no
//    longer evicts the 747 KB pe table from L2, so the gather path stays hot.
//  - manual 4x unroll of the grid-stride loop: 4 independent x loads + 4 pe
//    gathers in flight per iteration.
//  - grid = ceil(n4 / (256*16)) = 2920 blocks: exactly 16 float4/thread, tail
//    loop compiled but never runs for this shape.

typedef float f32x4 __attribute__((ext_vector_type(4)));

__global__ __launch_bounds__(256, 8)
void PositionalEncoding_80659485819003_kernel(
    const f32x4* __restrict__ x,
    const int*   __restrict__ positions,
    const f32x4* __restrict__ pe,
    f32x4*       __restrict__ out,
    int n4)
{
    const int stride = gridDim.x * blockDim.x;
    int i = blockIdx.x * blockDim.x + threadIdx.x;

    // Main unrolled loop: 4 independent stream-loads + gathers in flight.
    for (; i + 3 * stride < n4; i += 4 * stride) {
        const int i0 = i, i1 = i + stride, i2 = i + 2 * stride, i3 = i + 3 * stride;

        f32x4 v0 = __builtin_nontemporal_load(&x[i0]);
        f32x4 v1 = __builtin_nontemporal_load(&x[i1]);
        f32x4 v2 = __builtin_nontemporal_load(&x[i2]);
        f32x4 v3 = __builtin_nontemporal_load(&x[i3]);

        const int p0 = positions[i0 >> 7];
        const int p1 = positions[i1 >> 7];
        const int p2 = positions[i2 >> 7];
        const int p3 = positions[i3 >> 7];

        if (p0 >= 0) v0 += pe[(p0 << 7) + (i0 & 127)];
        if (p1 >= 0) v1 += pe[(p1 << 7) + (i1 & 127)];
        if (p2 >= 0) v2 += pe[(p2 << 7) + (i2 & 127)];
        if (p3 >= 0) v3 += pe[(p3 << 7) + (i3 & 127)];

        __builtin_nontemporal_store(v0, &out[i0]);
        __builtin_nontemporal_store(v1, &out[i1]);
        __builtin_nontemporal_store(v2, &out[i2]);
        __builtin_nontemporal_store(v3, &out[i3]);
    }

    // Tail (never runs for n4 = 11,960,320 with grid 2920, but keeps it correct).
    for (; i < n4; i += stride) {
        f32x4 v = __builtin_nontemporal_load(&x[i]);
        const int p = positions[i >> 7];
        if (p >= 0) v += pe[(p << 7) + (i & 127)];
        __builtin_nontemporal_store(v, &out[i]);
    }
}

extern "C" void kernel_launch(void* const* d_in, const int* in_sizes, int n_in,
                              void* d_out, int out_size, void* d_ws, size_t ws_size,
                              hipStream_t stream)
{
    const f32x4* x         = (const f32x4*)d_in[0];
    const int*   positions = (const int*)d_in[1];
    const f32x4* pe        = (const f32x4*)d_in[2];
    f32x4*       out       = (f32x4*)d_out;

    const int n4 = out_size / 4;               // 11,960,320 float4
    const int block = 256;
    const int iters_per_thread = 16;
    int grid = (n4 + block * iters_per_thread - 1) / (block * iters_per_thread);  // 2920

    PositionalEncoding_80659485819003_kernel<<<grid, block, 0, stream>>>(
        x, positions, pe, out, n4);
}

// Round 4
// 66.960 us; speedup vs baseline: 1.1388x; 1.1388x over previous
//
#include <hip/hip_runtime.h>

// PositionalEncoding: out[b,s,d] = x[b,s,d] + (positions[b,s] >= 0 ? pe[positions[b,s], d] : 0)
// B=256, S=365, D=512, fp32. Memory-bound: read x (191 MB) + write out (191 MB);
// positions (373 KB) and pe (747 KB) are cache-resident.
//
// Round 3 -> 4 (theory: DRAM page locality): grid-stride loops (2048-2920 blocks,
// strided jumps of ~46 MB per iteration) pinned at 5.04 TB/s. Switch to the
// canonical one-float4-per-thread flat grid (46,720 blocks) like the 7 TB/s
// fill kernels: blocks dispatch ~in order, so the global access stream is a
// moving contiguous window -> HBM row-buffer hits + L2 write combining.
// n4 = 11,960,320 = 256 * 46,720 exactly (no tail).

typedef float f32x4 __attribute__((ext_vector_type(4)));

__global__ __launch_bounds__(256, 8)
void PositionalEncoding_80659485819003_kernel(
    const f32x4* __restrict__ x,
    const int*   __restrict__ positions,
    const f32x4* __restrict__ pe,
    f32x4*       __restrict__ out,
    int n4)
{
    const int i = blockIdx.x * 256 + threadIdx.x;
    if (i >= n4) return;

    f32x4 v = __builtin_nontemporal_load(&x[i]);   // streaming read, don't pollute L2
    const int pos = positions[i >> 7];             // D/4 = 128 float4 per (b,s) row
    if (pos >= 0) {
        v += pe[(pos << 7) + (i & 127)];           // cached gather (pe = 747 KB, L2-resident)
    }
    __builtin_nontemporal_store(v, &out[i]);       // streaming write
}

extern "C" void kernel_launch(void* const* d_in, const int* in_sizes, int n_in,
                              void* d_out, int out_size, void* d_ws, size_t ws_size,
                              hipStream_t stream)
{
    const f32x4* x         = (const f32x4*)d_in[0];
    const int*   positions = (const int*)d_in[1];
    const f32x4* pe        = (const f32x4*)d_in[2];
    f32x4*       out       = (f32x4*)d_out;

    const int n4 = out_size / 4;                   // 11,960,320 float4
    const int block = 256;
    const int grid = (n4 + block - 1) / block;     // 46,720 blocks, exact fit

    PositionalEncoding_80659485819003_kernel<<<grid, block, 0, stream>>>(
        x, positions, pe, out, n4);
}